// Round 4
// baseline (217.034 us; speedup 1.0000x reference)
//
#include <hip/hip_runtime.h>
#include <hip/hip_bf16.h>

typedef __bf16 bf16;
typedef __attribute__((ext_vector_type(8))) __bf16 bf16x8;
typedef __attribute__((ext_vector_type(4))) __bf16 bf16x4;
typedef __attribute__((ext_vector_type(2))) __bf16 bf16x2;
typedef __attribute__((ext_vector_type(4))) float f32x4;

#define NB 2
#define NH 8
#define NL 2048
#define NE 64
#define NKV 2560

#define QN (NB*NH*NL*NE)    /* 2097152 */
#define KN (NB*NH*NKV*NE)   /* 2621440 */
#define VN KN
#define PEN (NH*NKV*NE)     /* 1310720 */

#define MFMA(a,b,c) __builtin_amdgcn_mfma_f32_16x16x32_bf16(a,b,c,0,0,0)

// ---------------- fp32 -> bf16 conversion of q,k,v,pe into workspace ----------------
extern "C" __global__ __launch_bounds__(256) void cvt_kernel(
    const float* __restrict__ q, const float* __restrict__ k,
    const float* __restrict__ v, const float* __restrict__ pe,
    bf16* __restrict__ ws)
{
  long i = ((long)blockIdx.x * 256 + threadIdx.x) * 4;
  const float* __restrict__ src;
  long off;
  if (i < QN)            { src = q;  off = i; }
  else if (i < QN+KN)    { src = k;  off = i - QN; }
  else if (i < QN+KN+VN) { src = v;  off = i - (QN+KN); }
  else                   { src = pe; off = i - (QN+KN+VN); }
  float4 f = *(const float4*)(src + off);
  bf16x4 o = { (bf16)f.x, (bf16)f.y, (bf16)f.z, (bf16)f.w };
  *(bf16x4*)(ws + i) = o;
}

// ---------------- main attention kernel ----------------
// Block: 256 thr = 4 waves; each wave owns 16 q rows; q-tile = 64; kv-tile = 64.
// bias(r,m) = q[r] . pe[2047+m-r]; computed as banded MFMA vs a staged 128-row PE window.
extern "C" __global__ __launch_bounds__(256, 2) void attn_kernel(
    const bf16* __restrict__ qb, const bf16* __restrict__ kb,
    const bf16* __restrict__ vb, const bf16* __restrict__ peb,
    float* __restrict__ out)
{
  // stride 72 (elems): rows stay 16B aligned for ds_read_b128; bank audit: K/PE/P optimal
  __shared__ bf16 Klds[64][72];
  __shared__ bf16 Vtlds[64][72];        // transposed: [e][key], XOR-swizzled cols
  __shared__ bf16 PElds[128][72];       // PE band rows
  __shared__ float Pposlds[4][16][84];  // per-wave band result [qrow][band idx], fp32
  __shared__ bf16 Plds[4][16][72];      // per-wave P (probs) staged for PV A-operand

  const int tid  = threadIdx.x;
  const int wave = tid >> 6;
  const int lane = tid & 63;
  const int g    = lane >> 4;   // 0..3
  const int c    = lane & 15;   // 0..15

  const int qtile = 31 - blockIdx.x;   // heavy tiles dispatch first
  const int h  = blockIdx.y;
  const int b  = blockIdx.z;
  const int bh = b * NH + h;
  const int r0  = qtile * 64;
  const int r0w = r0 + wave * 16;

  const bf16* __restrict__ qB  = qb  + (size_t)bh * NL  * NE;
  const bf16* __restrict__ kB  = kb  + (size_t)bh * NKV * NE;
  const bf16* __restrict__ vB  = vb  + (size_t)bh * NKV * NE;
  const bf16* __restrict__ peB = peb + (size_t)h  * NKV * NE;

  // Q fragments (A layout: row = lane%16, k = (lane/16)*8), held all loop
  bf16x8 aq[2];
#pragma unroll
  for (int ks = 0; ks < 2; ++ks)
    aq[ks] = *(const bf16x8*)(qB + (size_t)(r0w + c) * NE + ks*32 + g*8);

  const f32x4 ZERO = {0.f, 0.f, 0.f, 0.f};
  f32x4 O[4];
  float M2[4], Lsum[4];
#pragma unroll
  for (int i = 0; i < 4; ++i) { O[i] = ZERO; M2[i] = -3.0e38f; Lsum[i] = 0.f; }

  const int ntiles = qtile + 9;                     // exact: last key = r0+63+512
  const float COMB = 0.125f * 1.44269504088896f;    // scale * log2(e)

  for (int t = 0; t < ntiles; ++t) {
    const int m0 = t * 64;
    const int pebase = 2047 + m0 - r0 - 63;         // >= 0 always

    __syncthreads();   // protect previous iteration's LDS reads
    // ---- stage K tile [64 keys][64 e] ----
    {
      const int row = tid >> 2, seg = tid & 3;
      const bf16* s = kB + (size_t)(m0 + row) * NE + seg * 16;
      *(bf16x8*)&Klds[row][seg*16]   = *(const bf16x8*)(s);
      *(bf16x8*)&Klds[row][seg*16+8] = *(const bf16x8*)(s + 8);
    }
    // ---- stage V^T tile [64 e][64 keys], XOR-swizzled: col ^= (row>>3)<<3 ----
    // write bank = (i2*4 + (p ^ (cg<<2)))%32 -> exact 2-way (free); was 8-way
    {
      const int p = tid >> 3, cg = tid & 7;
      const bf16* s = vB + (size_t)(m0 + 2*p) * NE + cg * 8;
      bf16x8 v0 = *(const bf16x8*)(s);
      bf16x8 v1 = *(const bf16x8*)(s + NE);
      const int colw = (2*p) ^ (cg << 3);
#pragma unroll
      for (int i2 = 0; i2 < 8; ++i2) {
        bf16x2 pr = { v0[i2], v1[i2] };
        *(bf16x2*)&Vtlds[cg*8 + i2][colw] = pr;
      }
    }
    // ---- stage PE band [128 rows][64 e] ----
    {
      const int row = tid >> 1, seg = tid & 1;
      int prw = pebase + row;
      prw = prw < (NKV-1) ? prw : (NKV-1);          // rows past 2559 are masked anyway
      const bf16* s = peB + (size_t)prw * NE + seg * 32;
#pragma unroll
      for (int j = 0; j < 4; ++j)
        *(bf16x8*)&PElds[row][seg*32 + j*8] = *(const bf16x8*)(s + j*8);
    }
    __syncthreads();

    // ---- QK^T: S[sub] = Q(16) x K^T(16 keys per sub) ----
    f32x4 S[4];
#pragma unroll
    for (int sub = 0; sub < 4; ++sub) {
      S[sub] = ZERO;
#pragma unroll
      for (int ks = 0; ks < 2; ++ks) {
        bf16x8 bk = *(const bf16x8*)&Klds[sub*16 + c][ks*32 + g*8];
        S[sub] = MFMA(aq[ks], bk, S[sub]);
      }
    }
    // ---- pos band matmul: Ppos[r][j] = q[r] . pe[pebase+48-wave*16+j], j in [0,79] ----
    {
      const int bo = 48 - wave * 16;   // wave's band offset inside PElds
      f32x4 PP[5];
#pragma unroll
      for (int sub = 0; sub < 5; ++sub) {
        PP[sub] = ZERO;
#pragma unroll
        for (int ks = 0; ks < 2; ++ks) {
          bf16x8 bp = *(const bf16x8*)&PElds[bo + sub*16 + c][ks*32 + g*8];
          PP[sub] = MFMA(aq[ks], bp, PP[sub]);
        }
      }
#pragma unroll
      for (int sub = 0; sub < 5; ++sub)
#pragma unroll
        for (int reg = 0; reg < 4; ++reg)
          Pposlds[wave][g*4 + reg][sub*16 + c] = PP[sub][reg];
    }

    // compiler fence: Pposlds read below is a cross-lane dependency on the
    // same-wave writes above; alias analysis can't see it (zero HW cost)
    __builtin_amdgcn_wave_barrier();

    // ---- diagonal bias gather + scale (+ mask, last tile only) ----
    float sv[4][4];
#pragma unroll
    for (int sub = 0; sub < 4; ++sub)
#pragma unroll
      for (int reg = 0; reg < 4; ++reg) {
        const int idx = sub*16 + c - (g*4 + reg) + 15;     // in [0,78]
        float bias = Pposlds[wave][g*4 + reg][idx];
        sv[sub][reg] = (S[sub][reg] + bias) * COMB;        // log2 domain
      }
    if (t == ntiles - 1) {
#pragma unroll
      for (int sub = 0; sub < 4; ++sub)
#pragma unroll
        for (int reg = 0; reg < 4; ++reg)
          if (sub*16 + c > wave*16 + g*4 + reg) sv[sub][reg] = -3.0e38f;
    }

    // ---- online softmax (wave-parallel, 16-lane row groups) ----
    float pexp[4][4];
#pragma unroll
    for (int reg = 0; reg < 4; ++reg) {
      float m2 = fmaxf(fmaxf(sv[0][reg], sv[1][reg]), fmaxf(sv[2][reg], sv[3][reg]));
      m2 = fmaxf(m2, __shfl_xor(m2, 1, 16));
      m2 = fmaxf(m2, __shfl_xor(m2, 2, 16));
      m2 = fmaxf(m2, __shfl_xor(m2, 4, 16));
      m2 = fmaxf(m2, __shfl_xor(m2, 8, 16));
      const float Mn = fmaxf(M2[reg], m2);
      const float alpha = exp2f(M2[reg] - Mn);   // first tile: exp2(-inf) -> 0
      float rs = 0.f;
#pragma unroll
      for (int sub = 0; sub < 4; ++sub) {
        float p = exp2f(sv[sub][reg] - Mn);
        pexp[sub][reg] = p;
        rs += p;
      }
      rs += __shfl_xor(rs, 1, 16);
      rs += __shfl_xor(rs, 2, 16);
      rs += __shfl_xor(rs, 4, 16);
      rs += __shfl_xor(rs, 8, 16);
      Lsum[reg] = Lsum[reg] * alpha + rs;
      M2[reg] = Mn;
#pragma unroll
      for (int es = 0; es < 4; ++es) O[es][reg] *= alpha;
    }

    // ---- P -> LDS (C layout -> A layout fix-up via LDS) ----
#pragma unroll
    for (int sub = 0; sub < 4; ++sub)
#pragma unroll
      for (int reg = 0; reg < 4; ++reg)
        Plds[wave][g*4 + reg][sub*16 + c] = (bf16)pexp[sub][reg];

    // compiler fence: same cross-lane LDS dependency as above
    __builtin_amdgcn_wave_barrier();

    // ---- PV: O[es] += P(16x64) x V(64 x 16e per es) ----
#pragma unroll
    for (int ks = 0; ks < 2; ++ks) {
      bf16x8 ap = *(const bf16x8*)&Plds[wave][c][ks*32 + g*8];
#pragma unroll
      for (int es = 0; es < 4; ++es) {
        const int vrow = es*16 + c;
        const int vcol = (ks*32 + g*8) ^ ((vrow >> 3) << 3);   // match write swizzle
        bf16x8 bv = *(const bf16x8*)&Vtlds[vrow][vcol];
        O[es] = MFMA(ap, bv, O[es]);
      }
    }
  }

  // ---- epilogue: normalize and store [B, L, H*E] fp32 ----
  float rinv[4];
#pragma unroll
  for (int reg = 0; reg < 4; ++reg) rinv[reg] = 1.0f / Lsum[reg];
#pragma unroll
  for (int es = 0; es < 4; ++es)
#pragma unroll
    for (int reg = 0; reg < 4; ++reg) {
      const int r = r0w + g*4 + reg;
      out[((size_t)b * NL + r) * (NH*NE) + h * NE + es*16 + c] = O[es][reg] * rinv[reg];
    }
}

extern "C" void kernel_launch(void* const* d_in, const int* in_sizes, int n_in,
                              void* d_out, int out_size, void* d_ws, size_t ws_size,
                              hipStream_t stream)
{
  const float* q  = (const float*)d_in[0];
  const float* k  = (const float*)d_in[1];
  const float* v  = (const float*)d_in[2];
  const float* pe = (const float*)d_in[4];   // d_in[3] = attn_mask (unused, ==0)
  float* out = (float*)d_out;
  bf16* ws = (bf16*)d_ws;                    // needs 17.3 MB

  // total bf16 elems = QN+KN+VN+PEN = 8,650,752 ; /4 per thread /256 per block = 8448
  cvt_kernel<<<8448, 256, 0, stream>>>(q, k, v, pe, ws);
  attn_kernel<<<dim3(32, NH, NB), 256, 0, stream>>>(
      ws, ws + QN, ws + QN + KN, ws + QN + KN + VN, out);
}

// Round 5
// 175.917 us; speedup vs baseline: 1.2337x; 1.2337x over previous
//
#include <hip/hip_runtime.h>
#include <hip/hip_bf16.h>

typedef __bf16 bf16;
typedef __attribute__((ext_vector_type(8))) __bf16 bf16x8;
typedef __attribute__((ext_vector_type(4))) __bf16 bf16x4;
typedef __attribute__((ext_vector_type(2))) __bf16 bf16x2;
typedef __attribute__((ext_vector_type(4))) float f32x4;

#define NB 2
#define NH 8
#define NL 2048
#define NE 64
#define NKV 2560

#define QN (NB*NH*NL*NE)    /* 2097152 */
#define KN (NB*NH*NKV*NE)   /* 2621440 */
#define VN KN
#define PEN (NH*NKV*NE)     /* 1310720 */

#define MFMA(a,b,c) __builtin_amdgcn_mfma_f32_16x16x32_bf16(a,b,c,0,0,0)

// ---------------- fp32 -> bf16 conversion of q,k,v,pe into workspace ----------------
extern "C" __global__ __launch_bounds__(256) void cvt_kernel(
    const float* __restrict__ q, const float* __restrict__ k,
    const float* __restrict__ v, const float* __restrict__ pe,
    bf16* __restrict__ ws)
{
  long i = ((long)blockIdx.x * 256 + threadIdx.x) * 4;
  const float* __restrict__ src;
  long off;
  if (i < QN)            { src = q;  off = i; }
  else if (i < QN+KN)    { src = k;  off = i - QN; }
  else if (i < QN+KN+VN) { src = v;  off = i - (QN+KN); }
  else                   { src = pe; off = i - (QN+KN+VN); }
  float4 f = *(const float4*)(src + off);
  bf16x4 o = { (bf16)f.x, (bf16)f.y, (bf16)f.z, (bf16)f.w };
  *(bf16x4*)(ws + i) = o;
}

// ---------------- main attention kernel ----------------
// Block: 256 thr = 4 waves; each wave owns 16 q rows; q-tile = 64; kv-tile = 64.
// bias(r,m) = q[r] . pe[2047+m-r]: banded MFMA vs staged 128-row PE window, then
// in-register diagonal gather via width-16 shuffles (no LDS round-trip).
extern "C" __global__ __launch_bounds__(256, 2) void attn_kernel(
    const bf16* __restrict__ qb, const bf16* __restrict__ kb,
    const bf16* __restrict__ vb, const bf16* __restrict__ peb,
    float* __restrict__ out)
{
  // stride 72 (elems): rows 16B aligned for ds_read_b128; bank audit: K/PE/P reads optimal
  __shared__ bf16 Klds[64][72];
  __shared__ bf16 Vtlds[64][72];        // transposed: [e][key], XOR-swizzled cols
  __shared__ bf16 PElds[128][72];       // PE band rows
  __shared__ bf16 Plds[4][16][72];      // per-wave P (probs) staged for PV A-operand
  // total 46.1 KB (was 67.5: Pposlds removed)

  const int tid  = threadIdx.x;
  const int wave = tid >> 6;
  const int lane = tid & 63;
  const int g    = lane >> 4;   // 0..3
  const int c    = lane & 15;   // 0..15

  // Anti-correlated qtile mapping: co-resident ids {k, k+256} get qtiles
  // (31 - k%32) and (k%32) -> every CU's pair sums to 49 tile-units (balanced).
  const int id   = blockIdx.x;
  const int jm   = id & 255;
  const int half = id >> 8;
  const int qtile = half ? (jm & 31) : (31 - (jm & 31));
  const int hb = (half << 3) | (jm >> 5);   // 0..15
  const int h  = hb & 7;
  const int b  = hb >> 3;
  const int bh = b * NH + h;
  const int r0  = qtile * 64;
  const int r0w = r0 + wave * 16;

  const bf16* __restrict__ qB  = qb  + (size_t)bh * NL  * NE;
  const bf16* __restrict__ kB  = kb  + (size_t)bh * NKV * NE;
  const bf16* __restrict__ vB  = vb  + (size_t)bh * NKV * NE;
  const bf16* __restrict__ peB = peb + (size_t)h  * NKV * NE;

  // Q fragments (A layout: row = lane%16, k = (lane/16)*8), held all loop
  bf16x8 aq[2];
#pragma unroll
  for (int ks = 0; ks < 2; ++ks)
    aq[ks] = *(const bf16x8*)(qB + (size_t)(r0w + c) * NE + ks*32 + g*8);

  const f32x4 ZERO = {0.f, 0.f, 0.f, 0.f};
  f32x4 O[4];
  float M2[4], Lsum[4];
#pragma unroll
  for (int i = 0; i < 4; ++i) { O[i] = ZERO; M2[i] = -3.0e38f; Lsum[i] = 0.f; }

  const int ntiles = qtile + 9;                     // exact: last key = r0+63+512
  const float COMB = 0.125f * 1.44269504088896f;    // scale * log2(e)

  // T14 async-STAGE split: tile t+1's global loads issue during compute(t);
  // the vmcnt wait lands at next iteration's LDS writes (after the barrier).
  bf16x8 sk0, sk1, svv0, svv1, spe0, spe1, spe2, spe3;
  const int krow = tid >> 2, kseg = tid & 3;        // K staging coords
  const int vp   = tid >> 3, vcg  = tid & 7;        // V staging coords
  const int perow = tid >> 1, peseg = tid & 1;      // PE staging coords

#define LOADT(m0_, pebase_) do {                                             \
    { const bf16* s = kB + (size_t)((m0_) + krow) * NE + kseg * 16;          \
      sk0 = *(const bf16x8*)(s); sk1 = *(const bf16x8*)(s + 8); }            \
    { const bf16* s = vB + (size_t)((m0_) + 2*vp) * NE + vcg * 8;            \
      svv0 = *(const bf16x8*)(s); svv1 = *(const bf16x8*)(s + NE); }         \
    { int prw = (pebase_) + perow;                                           \
      prw = prw < (NKV-1) ? prw : (NKV-1);                                   \
      const bf16* s = peB + (size_t)prw * NE + peseg * 32;                   \
      spe0 = *(const bf16x8*)(s);      spe1 = *(const bf16x8*)(s + 8);       \
      spe2 = *(const bf16x8*)(s + 16); spe3 = *(const bf16x8*)(s + 24); }    \
  } while (0)

  const int pebase0 = 1984 - r0;   // 2047 + m0 - r0 - 63 at m0=0
  LOADT(0, pebase0);

  for (int t = 0; t < ntiles; ++t) {
    const int m0 = t * 64;

    __syncthreads();   // previous tile's LDS readers done
    // ---- regs -> LDS ----
    *(bf16x8*)&Klds[krow][kseg*16]   = sk0;
    *(bf16x8*)&Klds[krow][kseg*16+8] = sk1;
    {
      // XOR-swizzle: col ^= (row>>3)<<3; write bank exact 2-way (free), was 8-way
      const int colw = (2*vp) ^ (vcg << 3);
#pragma unroll
      for (int i2 = 0; i2 < 8; ++i2) {
        bf16x2 pr = { svv0[i2], svv1[i2] };
        *(bf16x2*)&Vtlds[vcg*8 + i2][colw] = pr;
      }
    }
    *(bf16x8*)&PElds[perow][peseg*32]      = spe0;
    *(bf16x8*)&PElds[perow][peseg*32 + 8]  = spe1;
    *(bf16x8*)&PElds[perow][peseg*32 + 16] = spe2;
    *(bf16x8*)&PElds[perow][peseg*32 + 24] = spe3;
    __syncthreads();

    // ---- issue next tile's loads now; latency hides under compute below ----
    if (t + 1 < ntiles) LOADT(m0 + 64, pebase0 + m0 + 64);

    // ---- QK^T: S[sub] = Q(16) x K^T(16 keys per sub) ----
    f32x4 S[4];
#pragma unroll
    for (int sub = 0; sub < 4; ++sub) {
      S[sub] = ZERO;
#pragma unroll
      for (int ks = 0; ks < 2; ++ks) {
        bf16x8 bk = *(const bf16x8*)&Klds[sub*16 + c][ks*32 + g*8];
        S[sub] = MFMA(aq[ks], bk, S[sub]);
      }
    }
    // ---- pos band matmul: PP[sub][reg] = Ppos[qr=g*4+reg][j=sub*16+c] ----
    f32x4 PP[5];
    {
      const int bo = 48 - wave * 16;   // wave's band offset inside PElds
#pragma unroll
      for (int sub = 0; sub < 5; ++sub) {
        PP[sub] = ZERO;
#pragma unroll
        for (int ks = 0; ks < 2; ++ks) {
          bf16x8 bp = *(const bf16x8*)&PElds[bo + sub*16 + c][ks*32 + g*8];
          PP[sub] = MFMA(aq[ks], bp, PP[sub]);
        }
      }
    }

    // ---- in-register diagonal gather: bias(qr,m) = Ppos[qr][m-qr+15] ----
    // source lane (same 16-group) = (c-qr+15)&15 for BOTH register candidates;
    // register = PP[sub + (c>qr)]
    float sv[4][4];
#pragma unroll
    for (int reg = 0; reg < 4; ++reg) {
      const int qr = g*4 + reg;
      const int srcc = (c - qr + 15) & 15;
      float sh[5];
#pragma unroll
      for (int s5 = 0; s5 < 5; ++s5) sh[s5] = __shfl(PP[s5][reg], srcc, 16);
      const bool sel = (c > qr);
#pragma unroll
      for (int sub = 0; sub < 4; ++sub) {
        const float bias = sel ? sh[sub+1] : sh[sub];
        sv[sub][reg] = (S[sub][reg] + bias) * COMB;   // log2 domain
      }
    }
    if (t == ntiles - 1) {
#pragma unroll
      for (int sub = 0; sub < 4; ++sub)
#pragma unroll
        for (int reg = 0; reg < 4; ++reg)
          if (sub*16 + c > wave*16 + g*4 + reg) sv[sub][reg] = -3.0e38f;
    }

    // ---- online softmax (wave-parallel, 16-lane row groups) ----
    float pexp[4][4];
#pragma unroll
    for (int reg = 0; reg < 4; ++reg) {
      float m2 = fmaxf(fmaxf(sv[0][reg], sv[1][reg]), fmaxf(sv[2][reg], sv[3][reg]));
      m2 = fmaxf(m2, __shfl_xor(m2, 1, 16));
      m2 = fmaxf(m2, __shfl_xor(m2, 2, 16));
      m2 = fmaxf(m2, __shfl_xor(m2, 4, 16));
      m2 = fmaxf(m2, __shfl_xor(m2, 8, 16));
      const float Mn = fmaxf(M2[reg], m2);
      const float alpha = exp2f(M2[reg] - Mn);   // first tile: exp2(-inf) -> 0
      float rs = 0.f;
#pragma unroll
      for (int sub = 0; sub < 4; ++sub) {
        float p = exp2f(sv[sub][reg] - Mn);
        pexp[sub][reg] = p;
        rs += p;
      }
      rs += __shfl_xor(rs, 1, 16);
      rs += __shfl_xor(rs, 2, 16);
      rs += __shfl_xor(rs, 4, 16);
      rs += __shfl_xor(rs, 8, 16);
      Lsum[reg] = Lsum[reg] * alpha + rs;
      M2[reg] = Mn;
#pragma unroll
      for (int es = 0; es < 4; ++es) O[es][reg] *= alpha;
    }

    // ---- P -> LDS (C layout -> A layout fix-up via LDS) ----
#pragma unroll
    for (int sub = 0; sub < 4; ++sub)
#pragma unroll
      for (int reg = 0; reg < 4; ++reg)
        Plds[wave][g*4 + reg][sub*16 + c] = (bf16)pexp[sub][reg];

    // compiler fence: cross-lane LDS dependency invisible to alias analysis
    __builtin_amdgcn_wave_barrier();

    // ---- PV: O[es] += P(16x64) x V(64 x 16e per es) ----
#pragma unroll
    for (int ks = 0; ks < 2; ++ks) {
      bf16x8 ap = *(const bf16x8*)&Plds[wave][c][ks*32 + g*8];
#pragma unroll
      for (int es = 0; es < 4; ++es) {
        const int vrow = es*16 + c;
        const int vcol = (ks*32 + g*8) ^ ((vrow >> 3) << 3);   // match write swizzle
        bf16x8 bv = *(const bf16x8*)&Vtlds[vrow][vcol];
        O[es] = MFMA(ap, bv, O[es]);
      }
    }
  }

  // ---- epilogue: normalize and store [B, L, H*E] fp32 ----
  float rinv[4];
#pragma unroll
  for (int reg = 0; reg < 4; ++reg) rinv[reg] = 1.0f / Lsum[reg];
#pragma unroll
  for (int es = 0; es < 4; ++es)
#pragma unroll
    for (int reg = 0; reg < 4; ++reg) {
      const int r = r0w + g*4 + reg;
      out[((size_t)b * NL + r) * (NH*NE) + h * NE + es*16 + c] = O[es][reg] * rinv[reg];
    }
}

extern "C" void kernel_launch(void* const* d_in, const int* in_sizes, int n_in,
                              void* d_out, int out_size, void* d_ws, size_t ws_size,
                              hipStream_t stream)
{
  const float* q  = (const float*)d_in[0];
  const float* k  = (const float*)d_in[1];
  const float* v  = (const float*)d_in[2];
  const float* pe = (const float*)d_in[4];   // d_in[3] = attn_mask (unused, ==0)
  float* out = (float*)d_out;
  bf16* ws = (bf16*)d_ws;                    // needs 17.3 MB

  // total bf16 elems = QN+KN+VN+PEN = 8,650,752 ; /4 per thread /256 per block = 8448
  cvt_kernel<<<8448, 256, 0, stream>>>(q, k, v, pe, ws);
  attn_kernel<<<512, 256, 0, stream>>>(
      ws, ws + QN, ws + QN + KN, ws + QN + KN + VN, out);
}

// Round 7
// 164.328 us; speedup vs baseline: 1.3207x; 1.0705x over previous
//
#include <hip/hip_runtime.h>
#include <hip/hip_bf16.h>

typedef __bf16 bf16;
typedef __attribute__((ext_vector_type(8))) __bf16 bf16x8;
typedef __attribute__((ext_vector_type(4))) __bf16 bf16x4;
typedef __attribute__((ext_vector_type(2))) __bf16 bf16x2;
typedef __attribute__((ext_vector_type(4))) float f32x4;

#define NB 2
#define NH 8
#define NL 2048
#define NE 64
#define NKV 2560

#define QN (NB*NH*NL*NE)    /* 2097152 */
#define KN (NB*NH*NKV*NE)   /* 2621440 */
#define VN KN
#define PEN (NH*NKV*NE)     /* 1310720 */

#define MFMA(a,b,c) __builtin_amdgcn_mfma_f32_16x16x32_bf16(a,b,c,0,0,0)

// ---- DPP rotate-reduce over 16-lane rows (VALU pipe; replaces ds_bpermute) ----
template<int CTRL>
__device__ __forceinline__ float fdpp(float x) {
  return __builtin_bit_cast(float,
    __builtin_amdgcn_update_dpp(0, __builtin_bit_cast(int, x), CTRL, 0xF, 0xF, true));
}
__device__ __forceinline__ float rowmax16(float x) {
  x = fmaxf(x, fdpp<0x121>(x));   // row_ror:1
  x = fmaxf(x, fdpp<0x122>(x));   // row_ror:2
  x = fmaxf(x, fdpp<0x124>(x));   // row_ror:4
  x = fmaxf(x, fdpp<0x128>(x));   // row_ror:8  -> all 16 lanes hold the max
  return x;
}
__device__ __forceinline__ float rowsum16(float x) {
  x += fdpp<0x121>(x);
  x += fdpp<0x122>(x);
  x += fdpp<0x124>(x);
  x += fdpp<0x128>(x);
  return x;
}

// ---------------- fp32 -> bf16 conversion of q,k,v,pe into workspace ----------------
extern "C" __global__ __launch_bounds__(256) void cvt_kernel(
    const float* __restrict__ q, const float* __restrict__ k,
    const float* __restrict__ v, const float* __restrict__ pe,
    bf16* __restrict__ ws)
{
  long i = ((long)blockIdx.x * 256 + threadIdx.x) * 8;   // all section sizes %8==0
  const float* __restrict__ src;
  long off;
  if (i < QN)            { src = q;  off = i; }
  else if (i < QN+KN)    { src = k;  off = i - QN; }
  else if (i < QN+KN+VN) { src = v;  off = i - (QN+KN); }
  else                   { src = pe; off = i - (QN+KN+VN); }
  float4 f0 = *(const float4*)(src + off);
  float4 f1 = *(const float4*)(src + off + 4);
  bf16x8 o = { (bf16)f0.x, (bf16)f0.y, (bf16)f0.z, (bf16)f0.w,
               (bf16)f1.x, (bf16)f1.y, (bf16)f1.z, (bf16)f1.w };
  *(bf16x8*)(ws + i) = o;
}

// ---------------- main attention kernel ----------------
// Block: 256 thr = 4 waves; each wave owns 16 q rows; q-tile = 64; kv-tile = 64.
// bias(r,m) = q[r] . pe[2047+m-r]: banded MFMA vs staged 128-row PE window, then
// in-register diagonal gather via width-16 shuffles; online softmax via DPP.
extern "C" __global__ __launch_bounds__(256, 2) void attn_kernel(
    const bf16* __restrict__ qb, const bf16* __restrict__ kb,
    const bf16* __restrict__ vb, const bf16* __restrict__ peb,
    float* __restrict__ out)
{
  // stride 72 (elems): rows 16B aligned for ds_read_b128; bank audit: K/PE/P reads optimal
  __shared__ bf16 Klds[64][72];
  __shared__ bf16 Vtlds[64][72];        // transposed: [e][key], XOR-swizzled cols
  __shared__ bf16 PElds[128][72];       // PE band rows
  __shared__ bf16 Plds[4][16][72];      // per-wave P (probs) staged for PV A-operand

  const int tid  = threadIdx.x;
  const int wave = tid >> 6;
  const int lane = tid & 63;
  const int g    = lane >> 4;   // 0..3
  const int c    = lane & 15;   // 0..15

  // Anti-correlated qtile mapping: co-resident ids {k, k+256} get qtiles
  // (31 - k%32) and (k%32) -> every CU's pair sums to 49 tile-units (balanced).
  const int id   = blockIdx.x;
  const int jm   = id & 255;
  const int half = id >> 8;
  const int qtile = half ? (jm & 31) : (31 - (jm & 31));
  const int hb = (half << 3) | (jm >> 5);   // 0..15
  const int h  = hb & 7;
  const int b  = hb >> 3;
  const int bh = b * NH + h;
  const int r0  = qtile * 64;
  const int r0w = r0 + wave * 16;

  const bf16* __restrict__ qB  = qb  + (size_t)bh * NL  * NE;
  const bf16* __restrict__ kB  = kb  + (size_t)bh * NKV * NE;
  const bf16* __restrict__ vB  = vb  + (size_t)bh * NKV * NE;
  const bf16* __restrict__ peB = peb + (size_t)h  * NKV * NE;

  // Q fragments (A layout: row = lane%16, k = (lane/16)*8), held all loop
  bf16x8 aq[2];
#pragma unroll
  for (int ks = 0; ks < 2; ++ks)
    aq[ks] = *(const bf16x8*)(qB + (size_t)(r0w + c) * NE + ks*32 + g*8);

  const f32x4 ZERO = {0.f, 0.f, 0.f, 0.f};
  f32x4 O[4];
  float M2[4], Lsum[4];
#pragma unroll
  for (int i = 0; i < 4; ++i) { O[i] = ZERO; M2[i] = -3.0e38f; Lsum[i] = 0.f; }

  const int ntiles = qtile + 9;                     // exact: last key = r0+63+512
  const float COMB = 0.125f * 1.44269504088896f;    // scale * log2(e)

  // T14 async-STAGE split: tile t+1's global loads issue during compute(t);
  // the vmcnt wait lands at next iteration's LDS writes (after the barrier).
  bf16x8 sk0, sk1, svv0, svv1, spe0, spe1, spe2, spe3;
  const int krow = tid >> 2, kseg = tid & 3;        // K staging coords
  const int vp   = tid >> 3, vcg  = tid & 7;        // V staging coords
  const int perow = tid >> 1, peseg = tid & 1;      // PE staging coords

#define LOADT(m0_, pebase_) do {                                             \
    { const bf16* s = kB + (size_t)((m0_) + krow) * NE + kseg * 16;          \
      sk0 = *(const bf16x8*)(s); sk1 = *(const bf16x8*)(s + 8); }            \
    { const bf16* s = vB + (size_t)((m0_) + 2*vp) * NE + vcg * 8;            \
      svv0 = *(const bf16x8*)(s); svv1 = *(const bf16x8*)(s + NE); }         \
    { int prw = (pebase_) + perow;                                           \
      prw = prw < (NKV-1) ? prw : (NKV-1);                                   \
      const bf16* s = peB + (size_t)prw * NE + peseg * 32;                   \
      spe0 = *(const bf16x8*)(s);      spe1 = *(const bf16x8*)(s + 8);       \
      spe2 = *(const bf16x8*)(s + 16); spe3 = *(const bf16x8*)(s + 24); }    \
  } while (0)

  const int pebase0 = 1984 - r0;   // 2047 + m0 - r0 - 63 at m0=0
  LOADT(0, pebase0);

  for (int t = 0; t < ntiles; ++t) {
    const int m0 = t * 64;

    __syncthreads();   // previous tile's LDS readers done
    // ---- regs -> LDS ----
    *(bf16x8*)&Klds[krow][kseg*16]   = sk0;
    *(bf16x8*)&Klds[krow][kseg*16+8] = sk1;
    {
      // XOR-swizzle: col ^= (row>>3)<<3; write bank exact 2-way (free), was 8-way
      const int colw = (2*vp) ^ (vcg << 3);
#pragma unroll
      for (int i2 = 0; i2 < 8; ++i2) {
        bf16x2 pr = { svv0[i2], svv1[i2] };
        *(bf16x2*)&Vtlds[vcg*8 + i2][colw] = pr;
      }
    }
    *(bf16x8*)&PElds[perow][peseg*32]      = spe0;
    *(bf16x8*)&PElds[perow][peseg*32 + 8]  = spe1;
    *(bf16x8*)&PElds[perow][peseg*32 + 16] = spe2;
    *(bf16x8*)&PElds[perow][peseg*32 + 24] = spe3;
    __syncthreads();

    // ---- issue next tile's loads now; latency hides under compute below ----
    if (t + 1 < ntiles) LOADT(m0 + 64, pebase0 + m0 + 64);

    // ---- QK^T: S[sub] = Q(16) x K^T(16 keys per sub) ----
    f32x4 S[4];
#pragma unroll
    for (int sub = 0; sub < 4; ++sub) {
      S[sub] = ZERO;
#pragma unroll
      for (int ks = 0; ks < 2; ++ks) {
        bf16x8 bk = *(const bf16x8*)&Klds[sub*16 + c][ks*32 + g*8];
        S[sub] = MFMA(aq[ks], bk, S[sub]);
      }
    }
    // ---- pos band matmul: PP[sub][reg] = Ppos[qr=g*4+reg][j=sub*16+c] ----
    f32x4 PP[5];
    {
      const int bo = 48 - wave * 16;   // wave's band offset inside PElds
#pragma unroll
      for (int sub = 0; sub < 5; ++sub) {
        PP[sub] = ZERO;
#pragma unroll
        for (int ks = 0; ks < 2; ++ks) {
          bf16x8 bp = *(const bf16x8*)&PElds[bo + sub*16 + c][ks*32 + g*8];
          PP[sub] = MFMA(aq[ks], bp, PP[sub]);
        }
      }
    }

    // ---- in-register diagonal gather: bias(qr,m) = Ppos[qr][m-qr+15] ----
    // source lane (same 16-group) = (c-qr+15)&15 for BOTH register candidates;
    // register = PP[sub + (c>qr)]
    float sv[4][4];
#pragma unroll
    for (int reg = 0; reg < 4; ++reg) {
      const int qr = g*4 + reg;
      const int srcc = (c - qr + 15) & 15;
      float sh[5];
#pragma unroll
      for (int s5 = 0; s5 < 5; ++s5) sh[s5] = __shfl(PP[s5][reg], srcc, 16);
      const bool sel = (c > qr);
#pragma unroll
      for (int sub = 0; sub < 4; ++sub) {
        const float bias = sel ? sh[sub+1] : sh[sub];
        sv[sub][reg] = (S[sub][reg] + bias) * COMB;   // log2 domain
      }
    }
    if (t == ntiles - 1) {
#pragma unroll
      for (int sub = 0; sub < 4; ++sub)
#pragma unroll
        for (int reg = 0; reg < 4; ++reg)
          if (sub*16 + c > wave*16 + g*4 + reg) sv[sub][reg] = -3.0e38f;
    }

    // ---- online softmax (wave-parallel; DPP rotate-reduce, no LDS traffic) ----
    float pexp[4][4];
#pragma unroll
    for (int reg = 0; reg < 4; ++reg) {
      float m2 = fmaxf(fmaxf(sv[0][reg], sv[1][reg]), fmaxf(sv[2][reg], sv[3][reg]));
      m2 = rowmax16(m2);
      const float Mn = fmaxf(M2[reg], m2);
      const float alpha = exp2f(M2[reg] - Mn);   // first tile: exp2(-inf) -> 0
      float rs = 0.f;
#pragma unroll
      for (int sub = 0; sub < 4; ++sub) {
        float p = exp2f(sv[sub][reg] - Mn);
        pexp[sub][reg] = p;
        rs += p;
      }
      rs = rowsum16(rs);
      Lsum[reg] = Lsum[reg] * alpha + rs;
      M2[reg] = Mn;
#pragma unroll
      for (int es = 0; es < 4; ++es) O[es][reg] *= alpha;
    }

    // ---- P -> LDS (C layout -> A layout fix-up via LDS) ----
#pragma unroll
    for (int sub = 0; sub < 4; ++sub)
#pragma unroll
      for (int reg = 0; reg < 4; ++reg)
        Plds[wave][g*4 + reg][sub*16 + c] = (bf16)pexp[sub][reg];

    // compiler fence: cross-lane LDS dependency invisible to alias analysis
    __builtin_amdgcn_wave_barrier();

    // ---- PV: O[es] += P(16x64) x V(64 x 16e per es) ----
#pragma unroll
    for (int ks = 0; ks < 2; ++ks) {
      bf16x8 ap = *(const bf16x8*)&Plds[wave][c][ks*32 + g*8];
#pragma unroll
      for (int es = 0; es < 4; ++es) {
        const int vrow = es*16 + c;
        const int vcol = (ks*32 + g*8) ^ ((vrow >> 3) << 3);   // match write swizzle
        bf16x8 bv = *(const bf16x8*)&Vtlds[vrow][vcol];
        O[es] = MFMA(ap, bv, O[es]);
      }
    }
  }

  // ---- epilogue: normalize and store [B, L, H*E] fp32 ----
  float rinv[4];
#pragma unroll
  for (int reg = 0; reg < 4; ++reg) rinv[reg] = 1.0f / Lsum[reg];
#pragma unroll
  for (int es = 0; es < 4; ++es)
#pragma unroll
    for (int reg = 0; reg < 4; ++reg) {
      const int r = r0w + g*4 + reg;
      out[((size_t)b * NL + r) * (NH*NE) + h * NE + es*16 + c] = O[es][reg] * rinv[reg];
    }
}

extern "C" void kernel_launch(void* const* d_in, const int* in_sizes, int n_in,
                              void* d_out, int out_size, void* d_ws, size_t ws_size,
                              hipStream_t stream)
{
  const float* q  = (const float*)d_in[0];
  const float* k  = (const float*)d_in[1];
  const float* v  = (const float*)d_in[2];
  const float* pe = (const float*)d_in[4];   // d_in[3] = attn_mask (unused, ==0)
  float* out = (float*)d_out;
  bf16* ws = (bf16*)d_ws;                    // needs 17.3 MB

  // total bf16 elems = QN+KN+VN+PEN = 8,650,752 ; /8 per thread /256 per block = 4224
  cvt_kernel<<<4224, 256, 0, stream>>>(q, k, v, pe, ws);
  attn_kernel<<<512, 256, 0, stream>>>(
      ws, ws + QN, ws + QN + KN, ws + QN + KN + VN, out);
}